// Round 4
// baseline (1027.158 us; speedup 1.0000x reference)
//
#include <hip/hip_runtime.h>
#include <stdint.h>

#define HW     65160      // H*W = 181*360
#define W_LON  360
#define H_LAT  181
#define T_OUT  181
#define NB     2
#define NC     128
#define NF     128
#define NK     3
#define NSEG   (NK * T_OUT)   // 543 segments, id = k*181 + t
#define RSTR   720            // sparse LDS row stride (floats)
#define TSTRIP 4              // t-values per sparse block
#define XROWS  65280          // padded hw rows for xt (255*256)

typedef __attribute__((ext_vector_type(8))) short bf16x8;
typedef __attribute__((ext_vector_type(4))) float f32x4;

#define AS1(p) ((const __attribute__((address_space(1))) void*)(p))
#define AS3(p) ((__attribute__((address_space(3))) void*)(p))

static __device__ inline ushort f2bf(float v) {
    unsigned u = __float_as_uint(v);
    unsigned r = (u + 0x7FFFu + ((u >> 16) & 1u)) >> 16;
    return (ushort)r;
}
static __device__ inline float bf2f(ushort h) {
    return __uint_as_float(((unsigned)h) << 16);
}

// ---------------- prep kernels ----------------

// weight (F,C,K) fp32 -> wt_h/wt_l [k][f][c] bf16 (c contiguous)
__global__ void k_transpose_w(const float* __restrict__ w,
                              ushort* __restrict__ wt_h, ushort* __restrict__ wt_l) {
    int i = blockIdx.x * 256 + threadIdx.x;
    if (i >= NK * NF * NC) return;
    int k = i / (NF * NC);
    int f = (i / NC) % NF;
    int c = i % NC;
    float v = w[(f * NC + c) * NK + k];
    ushort h = f2bf(v);
    ushort l = f2bf(v - bf2f(h));
    wt_h[i] = h;
    wt_l[i] = l;
}

__global__ void k_count(const int* __restrict__ seg, int* __restrict__ counts, int nnz) {
    int n = blockIdx.x * 256 + threadIdx.x;
    if (n >= nnz) return;
    atomicAdd(&counts[seg[n]], 1);
}

// parallel exclusive scan in entry-memory order (t outer, k inner)
__global__ void k_scan(const int* __restrict__ counts, int* __restrict__ row_start,
                       int* __restrict__ row_end) {
    __shared__ int buf[1024];
    int tid = threadIdx.x;
    int v = 0, s = 0;
    if (tid < NSEG) {
        int t = tid / NK, k = tid % NK;
        s = k * T_OUT + t;
        v = counts[s];
    }
    buf[tid] = v;
    __syncthreads();
    for (int d = 1; d < 1024; d <<= 1) {
        int x = (tid >= d) ? buf[tid - d] : 0;
        __syncthreads();
        buf[tid] += x;
        __syncthreads();
    }
    if (tid < NSEG) {
        row_end[s] = buf[tid];
        row_start[s] = buf[tid] - v;
    }
}

// pack each entry as (lds_offset, val*qw[lat]): ofs = dl*RSTR + lon, dl = lat-(t-3)
__global__ void k_pack(const int* __restrict__ seg, const int* __restrict__ lat,
                       const int* __restrict__ lon, const float* __restrict__ vals,
                       const float* __restrict__ qw,
                       uint2* __restrict__ packed, int nnz) {
    int n = blockIdx.x * 256 + threadIdx.x;
    if (n >= nnz) return;
    int s = seg[n];
    int k = s / T_OUT;
    int t = s - k * T_OUT;
    int la = lat[n];
    int dl = la - (t - 3);
    dl = max(0, min(6, dl));                  // mathematically always in [0,6]
    unsigned ofs = (unsigned)(dl * RSTR + lon[n]);
    float v = vals[n] * qw[la];               // fold quadrature weight into psi
    packed[n] = make_uint2(ofs, __float_as_uint(v));
}

// x [b][c][hw] fp32 -> xt_h/xt_l [b][hw][c] bf16 (c contiguous), via LDS transpose
__global__ __launch_bounds__(256) void k_split(const float* __restrict__ x,
                                               ushort* __restrict__ xt_h,
                                               ushort* __restrict__ xt_l) {
    int b = blockIdx.y;
    int hw0 = blockIdx.x * 32;
    __shared__ float t[128][33];
    int tid = threadIdx.x;
    int c = tid >> 1, j = tid & 1;
    const float* src = x + ((size_t)b * NC + c) * HW;
    if (hw0 + 32 <= HW) {
#pragma unroll
        for (int jj = 0; jj < 4; ++jj) {
            float4 v = *(const float4*)(src + hw0 + j * 16 + jj * 4);
            t[c][j * 16 + jj * 4 + 0] = v.x;
            t[c][j * 16 + jj * 4 + 1] = v.y;
            t[c][j * 16 + jj * 4 + 2] = v.z;
            t[c][j * 16 + jj * 4 + 3] = v.w;
        }
    } else {
        for (int e = 0; e < 16; ++e) {
            int hw = hw0 + j * 16 + e;
            t[c][j * 16 + e] = (hw < HW) ? src[hw] : 0.f;
        }
    }
    __syncthreads();
    int w = tid & 31, cg = tid >> 5;           // 32 hw x 8 groups of 16 c
    int hw = hw0 + w;
    if (hw < HW) {
        ushort hbuf[16], lbuf[16];
#pragma unroll
        for (int cc = 0; cc < 16; ++cc) {
            float v = t[cg * 16 + cc][w];
            ushort h = f2bf(v);
            hbuf[cc] = h;
            lbuf[cc] = f2bf(v - bf2f(h));
        }
        size_t off = ((size_t)b * XROWS + hw) * NC + cg * 16;
        *(int4*)(xt_h + off)     = *(int4*)hbuf;
        *(int4*)(xt_h + off + 8) = *(int4*)(hbuf + 8);
        *(int4*)(xt_l + off)     = *(int4*)lbuf;
        *(int4*)(xt_l + off + 8) = *(int4*)(lbuf + 8);
    }
}

// ---------------- stage 1: bf16x3 MFMA GEMM ----------------
// z[b][k][fl][hw] = sum_c W[f,c,k]*x[b,c,hw]  (fp32 via 3-pass bf16 MFMA, qw folded into psi)
template<int MT>
__global__ __launch_bounds__(256)
void k_gemm2(const ushort* __restrict__ xt_h, const ushort* __restrict__ xt_l,
             const ushort* __restrict__ wt_h, const ushort* __restrict__ wt_l,
             float* __restrict__ z, int cf0) {
    constexpr int MTILES = MT / 16;
    int tid = threadIdx.x;
    int bk = blockIdx.y;
    int b = bk / NK, k = bk % NK;
    int hwb = blockIdx.x * 256;

    __shared__ ushort smem[2 * MT * 32 + 2 * 256 * 32];
    ushort* Ah = smem;                  // MT rows x 32 c
    ushort* Al = smem + MT * 32;
    ushort* Bh = smem + 2 * MT * 32;    // 256 rows x 32 c
    ushort* Bl = Bh + 256 * 32;

    int lane = tid & 63;
    int wv = tid >> 6;
    int m = lane & 15, q0 = lane >> 4;
    int eoff = (m * 4 + (q0 ^ ((m >> 1) & 3))) * 8;   // ushort offset of this lane's chunk

    f32x4 acc[MTILES][4];
#pragma unroll
    for (int i = 0; i < MTILES; ++i)
#pragma unroll
        for (int j = 0; j < 4; ++j) acc[i][j] = (f32x4){0.f, 0.f, 0.f, 0.f};

    for (int c0 = 0; c0 < NC; c0 += 32) {
        if (tid < MT * 4) {
            int f = tid >> 2, s = tid & 3;
            int q = s ^ ((f >> 1) & 3);
            size_t gi = ((size_t)(k * NF + cf0 + f)) * NC + c0 + q * 8;
            int i0 = tid & ~63;
            __builtin_amdgcn_global_load_lds(AS1(wt_h + gi), AS3(Ah + i0 * 8), 16, 0, 0);
            __builtin_amdgcn_global_load_lds(AS1(wt_l + gi), AS3(Al + i0 * 8), 16, 0, 0);
        }
#pragma unroll
        for (int it = 0; it < 4; ++it) {
            int i = it * 256 + tid;
            int r = i >> 2, s = i & 3;
            int q = s ^ ((r >> 1) & 3);
            size_t gi = ((size_t)b * XROWS + hwb + r) * NC + c0 + q * 8;
            int i0 = i & ~63;
            __builtin_amdgcn_global_load_lds(AS1(xt_h + gi), AS3(Bh + i0 * 8), 16, 0, 0);
            __builtin_amdgcn_global_load_lds(AS1(xt_l + gi), AS3(Bl + i0 * 8), 16, 0, 0);
        }
        __syncthreads();

        bf16x8 ah[MTILES], al[MTILES], bh[4], bl[4];
#pragma unroll
        for (int mt = 0; mt < MTILES; ++mt) {
            ah[mt] = *(const bf16x8*)(Ah + mt * 512 + eoff);
            al[mt] = *(const bf16x8*)(Al + mt * 512 + eoff);
        }
#pragma unroll
        for (int nt = 0; nt < 4; ++nt) {
            int boff = wv * 2048 + nt * 512 + eoff;
            bh[nt] = *(const bf16x8*)(Bh + boff);
            bl[nt] = *(const bf16x8*)(Bl + boff);
        }
#pragma unroll
        for (int mt = 0; mt < MTILES; ++mt)
#pragma unroll
            for (int nt = 0; nt < 4; ++nt) {
                acc[mt][nt] = __builtin_amdgcn_mfma_f32_16x16x32_bf16(ah[mt], bh[nt], acc[mt][nt], 0, 0, 0);
                acc[mt][nt] = __builtin_amdgcn_mfma_f32_16x16x32_bf16(ah[mt], bl[nt], acc[mt][nt], 0, 0, 0);
                acc[mt][nt] = __builtin_amdgcn_mfma_f32_16x16x32_bf16(al[mt], bh[nt], acc[mt][nt], 0, 0, 0);
            }
        __syncthreads();
    }

#pragma unroll
    for (int mt = 0; mt < MTILES; ++mt)
#pragma unroll
        for (int nt = 0; nt < 4; ++nt) {
            int n = hwb + wv * 64 + nt * 16 + m;
            if (n < HW) {
                f32x4 a = acc[mt][nt];
#pragma unroll
                for (int r = 0; r < 4; ++r) {
                    int fl = mt * 16 + q0 * 4 + r;
                    z[((size_t)(b * NK + k) * MT + fl) * HW + n] = a[r];
                }
            }
        }
}

// ---------------- stage 2: gather/accumulate + bias ----------------
// block = (channel ch, t-strip of TSTRIP). Per k-plane: stage (TSTRIP+6) lat
// rows once (x2 lon dup, stride 720), then run TSTRIP entry loops against the
// same LDS image (entry for t0+dt adds dt*RSTR to its packed offset).
// LDS = (TSTRIP+6)*720*4 + pad ~= 29.6 KB -> 5 blocks/CU, 15 waves/CU.
__global__ void __launch_bounds__(192)
k_sparse(const float* __restrict__ z, const uint2* __restrict__ packed,
         const int* __restrict__ row_start, const int* __restrict__ row_end,
         const float* __restrict__ bias,
         float* __restrict__ out, int cf0, int CF) {
    int t0 = blockIdx.y * TSTRIP;
    int ch = blockIdx.x;                 // [0, 2*CF)
    int b  = ch / CF;
    int fl = ch % CF;
    int fg = cf0 + fl;
    int tid = threadIdx.x;               // 192
    __shared__ float lds[(TSTRIP + 6) * RSTR + 192];  // pad absorbs unused-lane overreads

    int lat0 = t0 - 3;
    float acc[TSTRIP][2];
#pragma unroll
    for (int dt = 0; dt < TSTRIP; ++dt) { acc[dt][0] = 0.f; acc[dt][1] = 0.f; }

    for (int k = 0; k < NK; ++k) {
        __syncthreads();   // previous phase's readers done before overwrite
        const float* zplane = &z[(size_t)((b * NK + k) * CF + fl) * HW];
        for (int q = tid; q < (TSTRIP + 6) * 90; q += 192) {
            int r = q / 90, s4 = (q - r * 90) * 4;
            int la = lat0 + r;
            if (la < 0 || la >= H_LAT) continue;   // rows never referenced by entries
            float4 v4 = *(const float4*)&zplane[la * W_LON + s4];
            *(float4*)&lds[r * RSTR + s4]       = v4;
            *(float4*)&lds[r * RSTR + 360 + s4] = v4;
        }
        __syncthreads();

#pragma unroll
        for (int dt = 0; dt < TSTRIP; ++dt) {
            int t = t0 + dt;
            if (t >= T_OUT) break;
            int s = k * T_OUT + t;
            int ns = row_start[s], ne = row_end[s];
            int toff = dt * RSTR + tid;
#pragma unroll 4
            for (int n = ns; n < ne; ++n) {
                uint2 e = packed[n];
                float v = __uint_as_float(e.y);
                int base = (int)e.x + toff;
                acc[dt][0] = fmaf(v, lds[base], acc[dt][0]);
                acc[dt][1] = fmaf(v, lds[base + 180], acc[dt][1]);
            }
        }
    }

    if (tid < 180) {
        float bs = bias[fg];
#pragma unroll
        for (int dt = 0; dt < TSTRIP; ++dt) {
            int t = t0 + dt;
            if (t >= T_OUT) break;
            size_t ob = (size_t)((b * NF + fg) * T_OUT + t) * W_LON;
            out[ob + tid]       = acc[dt][0] + bs;
            out[ob + tid + 180] = acc[dt][1] + bs;
        }
    }
}

// ---------------- launch ----------------
extern "C" void kernel_launch(void* const* d_in, const int* in_sizes, int n_in,
                              void* d_out, int out_size, void* d_ws, size_t ws_size,
                              hipStream_t stream) {
    const float* x    = (const float*)d_in[0];
    const float* qw   = (const float*)d_in[1];
    const float* vals = (const float*)d_in[2];
    const float* w    = (const float*)d_in[3];
    const float* bias = (const float*)d_in[4];
    const int*   seg  = (const int*)d_in[5];
    const int*   lat  = (const int*)d_in[6];
    const int*   lon  = (const int*)d_in[7];
    int nnz = in_sizes[2];
    float* out = (float*)d_out;

    char* wsb = (char*)d_ws;
    ushort* wt_h     = (ushort*)wsb;                        // 98304 B
    ushort* wt_l     = (ushort*)(wsb + 98304);              // 98304 B
    int*    counts   = (int*)(wsb + 196608);                // 2304 B
    int*    row_start= (int*)(wsb + 198912);                // 2304 B
    int*    row_end  = (int*)(wsb + 201216);                // 2304 B
    uint2*  packed   = (uint2*)(wsb + 203520);              // nnz*8 B
    size_t xoff = (203520 + (size_t)nnz * 8 + 255) & ~(size_t)255;
    size_t xtsz = (size_t)NB * XROWS * NC * 2;              // 33,423,360 B each
    ushort* xt_h = (ushort*)(wsb + xoff);
    ushort* xt_l = (ushort*)(wsb + xoff + xtsz);
    size_t zoff = (xoff + 2 * xtsz + 255) & ~(size_t)255;
    float* z = (float*)(wsb + zoff);
    size_t zavail = (ws_size > zoff) ? ws_size - zoff : 0;

    int CF = 16;
    if      (zavail >= (size_t)64 * 6 * HW * 4) CF = 64;
    else if (zavail >= (size_t)32 * 6 * HW * 4) CF = 32;

    hipMemsetAsync(counts, 0, NSEG * 4, stream);
    k_transpose_w<<<(NK * NF * NC + 255) / 256, 256, 0, stream>>>(w, wt_h, wt_l);
    k_count<<<(nnz + 255) / 256, 256, 0, stream>>>(seg, counts, nnz);
    k_scan<<<1, 1024, 0, stream>>>(counts, row_start, row_end);
    k_pack<<<(nnz + 255) / 256, 256, 0, stream>>>(seg, lat, lon, vals, qw, packed, nnz);
    k_split<<<dim3((HW + 31) / 32, NB), 256, 0, stream>>>(x, xt_h, xt_l);

    int hwtiles = (HW + 255) / 256;   // 255
    int tstrips = (T_OUT + TSTRIP - 1) / TSTRIP;
    for (int cf0 = 0; cf0 < NF; cf0 += CF) {
        dim3 gg(hwtiles, NB * NK);
        if (CF == 64)      k_gemm2<64><<<gg, 256, 0, stream>>>(xt_h, xt_l, wt_h, wt_l, z, cf0);
        else if (CF == 32) k_gemm2<32><<<gg, 256, 0, stream>>>(xt_h, xt_l, wt_h, wt_l, z, cf0);
        else               k_gemm2<16><<<gg, 256, 0, stream>>>(xt_h, xt_l, wt_h, wt_l, z, cf0);
        dim3 gs(2 * CF, tstrips);
        k_sparse<<<gs, 192, 0, stream>>>(z, packed, row_start, row_end, bias, out, cf0, CF);
    }
}

// Round 5
// 733.732 us; speedup vs baseline: 1.3999x; 1.3999x over previous
//
#include <hip/hip_runtime.h>
#include <stdint.h>

#define HW     65160      // H*W = 181*360
#define W_LON  360
#define H_LAT  181
#define T_OUT  181
#define NB     2
#define NC     128
#define NF     128
#define NK     3
#define NSEG   (NK * T_OUT)   // 543 segments, id = k*181 + t
#define RSTR   720            // sparse LDS row stride (floats)
#define XROWS  65280          // padded hw rows for xt (255*256)

typedef __attribute__((ext_vector_type(8))) short bf16x8;
typedef __attribute__((ext_vector_type(4))) float f32x4;

#define AS1(p) ((const __attribute__((address_space(1))) void*)(p))
#define AS3(p) ((__attribute__((address_space(3))) void*)(p))

static __device__ inline ushort f2bf(float v) {
    unsigned u = __float_as_uint(v);
    unsigned r = (u + 0x7FFFu + ((u >> 16) & 1u)) >> 16;
    return (ushort)r;
}
static __device__ inline float bf2f(ushort h) {
    return __uint_as_float(((unsigned)h) << 16);
}

// ---------------- prep kernels ----------------

// weight (F,C,K) fp32 -> wt_h/wt_l [k][f][c] bf16 (c contiguous)
__global__ void k_transpose_w(const float* __restrict__ w,
                              ushort* __restrict__ wt_h, ushort* __restrict__ wt_l) {
    int i = blockIdx.x * 256 + threadIdx.x;
    if (i >= NK * NF * NC) return;
    int k = i / (NF * NC);
    int f = (i / NC) % NF;
    int c = i % NC;
    float v = w[(f * NC + c) * NK + k];
    ushort h = f2bf(v);
    ushort l = f2bf(v - bf2f(h));
    wt_h[i] = h;
    wt_l[i] = l;
}

// segment bounds via binary search: entry order is t-major then k, so
// key(n) = (seg%181)*3 + seg/181 is monotone non-decreasing in n.
__global__ void k_bounds(const int* __restrict__ seg, int* __restrict__ row_start,
                         int* __restrict__ row_end, int nnz) {
    int s = blockIdx.x * 256 + threadIdx.x;
    if (s >= NSEG) return;
    int t = s % T_OUT, k = s / T_OUT;
    int key = t * NK + k;
    int lo = 0, hi = nnz;
    while (lo < hi) {                      // lower_bound
        int mid = (lo + hi) >> 1;
        int sm = seg[mid];
        int km = (sm % T_OUT) * NK + sm / T_OUT;
        if (km < key) lo = mid + 1; else hi = mid;
    }
    row_start[s] = lo;
    int lo2 = lo; hi = nnz;
    while (lo2 < hi) {                     // upper_bound
        int mid = (lo2 + hi) >> 1;
        int sm = seg[mid];
        int km = (sm % T_OUT) * NK + sm / T_OUT;
        if (km <= key) lo2 = mid + 1; else hi = mid;
    }
    row_end[s] = lo2;
}

// pack each entry as (lds_offset, val*qw[lat]): ofs = dl*RSTR + lon, dl = lat-(t-3)
__global__ void k_pack(const int* __restrict__ seg, const int* __restrict__ lat,
                       const int* __restrict__ lon, const float* __restrict__ vals,
                       const float* __restrict__ qw,
                       uint2* __restrict__ packed, int nnz) {
    int n = blockIdx.x * 256 + threadIdx.x;
    if (n >= nnz) return;
    int s = seg[n];
    int k = s / T_OUT;
    int t = s - k * T_OUT;
    int la = lat[n];
    int dl = la - (t - 3);
    dl = max(0, min(6, dl));                  // mathematically always in [0,6]
    unsigned ofs = (unsigned)(dl * RSTR + lon[n]);
    float v = vals[n] * qw[la];               // fold quadrature weight into psi
    packed[n] = make_uint2(ofs, __float_as_uint(v));
}

// x [b][c][hw] fp32 -> xt_h/xt_l [b][hw][c] bf16 (c contiguous).
// 64-wide hw tile: reads are 256B-contiguous float4 segments per 16 lanes;
// writes are 4KB-contiguous per wave (64 lanes x 64B span each).
__global__ __launch_bounds__(256) void k_split(const float* __restrict__ x,
                                               ushort* __restrict__ xt_h,
                                               ushort* __restrict__ xt_l) {
    int b = blockIdx.y;
    int hw0 = blockIdx.x * 64;
    __shared__ float t[128][65];
    int tid = threadIdx.x;
    int quad = tid & 15;              // 16 quads = 64 floats per row
    int r0 = tid >> 4;                // 16 rows per iteration
    bool full = (hw0 + 64 <= HW);
#pragma unroll
    for (int rr = 0; rr < 8; ++rr) {
        int c = rr * 16 + r0;
        const float* src = x + ((size_t)b * NC + c) * HW + hw0 + quad * 4;
        float4 v;
        if (full) {
            v = *(const float4*)src;
        } else {
            int base = hw0 + quad * 4;
            v.x = (base + 0 < HW) ? src[0] : 0.f;
            v.y = (base + 1 < HW) ? src[1] : 0.f;
            v.z = (base + 2 < HW) ? src[2] : 0.f;
            v.w = (base + 3 < HW) ? src[3] : 0.f;
        }
        *(float4*)&t[c][quad * 4] = v;
    }
    __syncthreads();
    int hwl = tid >> 2;               // 64 hw per block
    int c0 = (tid & 3) * 32;          // 4 c-chunks of 32
    int hw = hw0 + hwl;
    if (hw < HW) {
        ushort hb[32], lb[32];
#pragma unroll
        for (int cc = 0; cc < 32; ++cc) {
            float v = t[c0 + cc][hwl];
            ushort h = f2bf(v);
            hb[cc] = h;
            lb[cc] = f2bf(v - bf2f(h));
        }
        size_t off = ((size_t)b * XROWS + hw) * NC + c0;
#pragma unroll
        for (int j = 0; j < 4; ++j) {
            *(int4*)(xt_h + off + j * 8) = *(int4*)(hb + j * 8);
            *(int4*)(xt_l + off + j * 8) = *(int4*)(lb + j * 8);
        }
    }
}

// ---------------- stage 1: bf16x3 MFMA GEMM ----------------
// z[b][k][fl][hw] = sum_c W[f,c,k]*x[b,c,hw]  (fp32 via 3-pass bf16 MFMA, qw folded into psi)
template<int MT>
__global__ __launch_bounds__(256)
void k_gemm2(const ushort* __restrict__ xt_h, const ushort* __restrict__ xt_l,
             const ushort* __restrict__ wt_h, const ushort* __restrict__ wt_l,
             float* __restrict__ z, int cf0) {
    constexpr int MTILES = MT / 16;
    int tid = threadIdx.x;
    int bk = blockIdx.y;
    int b = bk / NK, k = bk % NK;
    int hwb = blockIdx.x * 256;

    __shared__ ushort smem[2 * MT * 32 + 2 * 256 * 32];
    ushort* Ah = smem;                  // MT rows x 32 c
    ushort* Al = smem + MT * 32;
    ushort* Bh = smem + 2 * MT * 32;    // 256 rows x 32 c
    ushort* Bl = Bh + 256 * 32;

    int lane = tid & 63;
    int wv = tid >> 6;
    int m = lane & 15, q0 = lane >> 4;
    int eoff = (m * 4 + (q0 ^ ((m >> 1) & 3))) * 8;   // ushort offset of this lane's chunk

    f32x4 acc[MTILES][4];
#pragma unroll
    for (int i = 0; i < MTILES; ++i)
#pragma unroll
        for (int j = 0; j < 4; ++j) acc[i][j] = (f32x4){0.f, 0.f, 0.f, 0.f};

    for (int c0 = 0; c0 < NC; c0 += 32) {
        if (tid < MT * 4) {
            int f = tid >> 2, s = tid & 3;
            int q = s ^ ((f >> 1) & 3);
            size_t gi = ((size_t)(k * NF + cf0 + f)) * NC + c0 + q * 8;
            int i0 = tid & ~63;
            __builtin_amdgcn_global_load_lds(AS1(wt_h + gi), AS3(Ah + i0 * 8), 16, 0, 0);
            __builtin_amdgcn_global_load_lds(AS1(wt_l + gi), AS3(Al + i0 * 8), 16, 0, 0);
        }
#pragma unroll
        for (int it = 0; it < 4; ++it) {
            int i = it * 256 + tid;
            int r = i >> 2, s = i & 3;
            int q = s ^ ((r >> 1) & 3);
            size_t gi = ((size_t)b * XROWS + hwb + r) * NC + c0 + q * 8;
            int i0 = i & ~63;
            __builtin_amdgcn_global_load_lds(AS1(xt_h + gi), AS3(Bh + i0 * 8), 16, 0, 0);
            __builtin_amdgcn_global_load_lds(AS1(xt_l + gi), AS3(Bl + i0 * 8), 16, 0, 0);
        }
        __syncthreads();

        bf16x8 ah[MTILES], al[MTILES], bh[4], bl[4];
#pragma unroll
        for (int mt = 0; mt < MTILES; ++mt) {
            ah[mt] = *(const bf16x8*)(Ah + mt * 512 + eoff);
            al[mt] = *(const bf16x8*)(Al + mt * 512 + eoff);
        }
#pragma unroll
        for (int nt = 0; nt < 4; ++nt) {
            int boff = wv * 2048 + nt * 512 + eoff;
            bh[nt] = *(const bf16x8*)(Bh + boff);
            bl[nt] = *(const bf16x8*)(Bl + boff);
        }
#pragma unroll
        for (int mt = 0; mt < MTILES; ++mt)
#pragma unroll
            for (int nt = 0; nt < 4; ++nt) {
                acc[mt][nt] = __builtin_amdgcn_mfma_f32_16x16x32_bf16(ah[mt], bh[nt], acc[mt][nt], 0, 0, 0);
                acc[mt][nt] = __builtin_amdgcn_mfma_f32_16x16x32_bf16(ah[mt], bl[nt], acc[mt][nt], 0, 0, 0);
                acc[mt][nt] = __builtin_amdgcn_mfma_f32_16x16x32_bf16(al[mt], bh[nt], acc[mt][nt], 0, 0, 0);
            }
        __syncthreads();
    }

#pragma unroll
    for (int mt = 0; mt < MTILES; ++mt)
#pragma unroll
        for (int nt = 0; nt < 4; ++nt) {
            int n = hwb + wv * 64 + nt * 16 + m;
            if (n < HW) {
                f32x4 a = acc[mt][nt];
#pragma unroll
                for (int r = 0; r < 4; ++r) {
                    int fl = mt * 16 + q0 * 4 + r;
                    z[((size_t)(b * NK + k) * MT + fl) * HW + n] = a[r];
                }
            }
        }
}

// ---------------- stage 2: gather/accumulate + bias (R2 structure, measured 232us) ----------------
// block = (channel ch, t); 192 threads; k-planes sequential, 7 rows x2 lon dup.
// LDS = 20480 B -> 8 blocks/CU, 24 waves/CU.
__global__ void __launch_bounds__(192)
k_sparse(const float* __restrict__ z, const uint2* __restrict__ packed,
         const int* __restrict__ row_start, const int* __restrict__ row_end,
         const float* __restrict__ bias,
         float* __restrict__ out, int cf0, int CF) {
    int t  = blockIdx.y;
    int ch = blockIdx.x;                 // [0, 2*CF)
    int b  = ch / CF;
    int fl = ch % CF;
    int fg = cf0 + fl;
    int tid = threadIdx.x;               // 192
    __shared__ float lds[7 * RSTR];      // 20160 B

    int lat0 = t - 3;
    float acc1 = 0.f, acc2 = 0.f;

    for (int k = 0; k < NK; ++k) {
        __syncthreads();
        const float* zplane = &z[(size_t)((b * NK + k) * CF + fl) * HW];
        for (int q = tid; q < 7 * 90; q += 192) {
            int r = q / 90, s4 = (q - r * 90) * 4;
            int la = lat0 + r;
            if (la < 0 || la >= H_LAT) continue;
            float4 v4 = *(const float4*)&zplane[la * W_LON + s4];
            *(float4*)&lds[r * RSTR + s4]       = v4;
            *(float4*)&lds[r * RSTR + 360 + s4] = v4;
        }
        __syncthreads();

        int s = k * T_OUT + t;
        int ns = row_start[s], ne = row_end[s];
#pragma unroll 4
        for (int n = ns; n < ne; ++n) {
            uint2 e = packed[n];
            float v = __uint_as_float(e.y);
            int base = (int)e.x + tid;
            acc1 = fmaf(v, lds[base], acc1);
            acc2 = fmaf(v, lds[base + 180], acc2);
        }
    }

    if (tid < 180) {
        float bs = bias[fg];
        size_t ob = (size_t)((b * NF + fg) * T_OUT + t) * W_LON;
        out[ob + tid]       = acc1 + bs;
        out[ob + tid + 180] = acc2 + bs;
    }
}

// ---------------- launch ----------------
extern "C" void kernel_launch(void* const* d_in, const int* in_sizes, int n_in,
                              void* d_out, int out_size, void* d_ws, size_t ws_size,
                              hipStream_t stream) {
    const float* x    = (const float*)d_in[0];
    const float* qw   = (const float*)d_in[1];
    const float* vals = (const float*)d_in[2];
    const float* w    = (const float*)d_in[3];
    const float* bias = (const float*)d_in[4];
    const int*   seg  = (const int*)d_in[5];
    const int*   lat  = (const int*)d_in[6];
    const int*   lon  = (const int*)d_in[7];
    int nnz = in_sizes[2];
    float* out = (float*)d_out;

    char* wsb = (char*)d_ws;
    ushort* wt_h     = (ushort*)wsb;                        // 98304 B
    ushort* wt_l     = (ushort*)(wsb + 98304);              // 98304 B
    int*    row_start= (int*)(wsb + 196608);                // 2304 B
    int*    row_end  = (int*)(wsb + 198912);                // 2304 B
    uint2*  packed   = (uint2*)(wsb + 201216);              // nnz*8 B
    size_t xoff = (201216 + (size_t)nnz * 8 + 255) & ~(size_t)255;
    size_t xtsz = (size_t)NB * XROWS * NC * 2;              // 33,423,360 B each
    ushort* xt_h = (ushort*)(wsb + xoff);
    ushort* xt_l = (ushort*)(wsb + xoff + xtsz);
    size_t zoff = (xoff + 2 * xtsz + 255) & ~(size_t)255;
    float* z = (float*)(wsb + zoff);
    size_t zavail = (ws_size > zoff) ? ws_size - zoff : 0;

    int CF = 16;
    if      (zavail >= (size_t)64 * 6 * HW * 4) CF = 64;
    else if (zavail >= (size_t)32 * 6 * HW * 4) CF = 32;

    k_transpose_w<<<(NK * NF * NC + 255) / 256, 256, 0, stream>>>(w, wt_h, wt_l);
    k_pack<<<(nnz + 255) / 256, 256, 0, stream>>>(seg, lat, lon, vals, qw, packed, nnz);
    k_bounds<<<(NSEG + 255) / 256, 256, 0, stream>>>(seg, row_start, row_end, nnz);
    k_split<<<dim3((HW + 63) / 64, NB), 256, 0, stream>>>(x, xt_h, xt_l);

    int hwtiles = (HW + 255) / 256;   // 255
    for (int cf0 = 0; cf0 < NF; cf0 += CF) {
        dim3 gg(hwtiles, NB * NK);
        if (CF == 64)      k_gemm2<64><<<gg, 256, 0, stream>>>(xt_h, xt_l, wt_h, wt_l, z, cf0);
        else if (CF == 32) k_gemm2<32><<<gg, 256, 0, stream>>>(xt_h, xt_l, wt_h, wt_l, z, cf0);
        else               k_gemm2<16><<<gg, 256, 0, stream>>>(xt_h, xt_l, wt_h, wt_l, z, cf0);
        dim3 gs(2 * CF, T_OUT);
        k_sparse<<<gs, 192, 0, stream>>>(z, packed, row_start, row_end, bias, out, cf0, CF);
    }
}